// Round 14
// baseline (3131.155 us; speedup 1.0000x reference)
//
#include <hip/hip_runtime.h>
#include <hip/hip_fp16.h>

#define B_   16
#define T_   4096
#define DIN  256
#define H_   128
#define G3   384   // 3*H

// exponent prescales: sigmoid -> rcp(1+exp2(-log2e * x)), tanh via sigmoid(2x)
#define SC_RZ 1.4426950408889634f
#define SC_N  2.8853900817779268f

typedef _Float16 half2_t __attribute__((ext_vector_type(2)));

__device__ __forceinline__ float fdot2(unsigned int a, unsigned int b, float c) {
#if __has_builtin(__builtin_amdgcn_fdot2)
  return __builtin_amdgcn_fdot2(__builtin_bit_cast(half2_t, a),
                                __builtin_bit_cast(half2_t, b), c, false);
#else
  const __half2 ha = __builtin_bit_cast(__half2, a);
  const __half2 hb = __builtin_bit_cast(__half2, b);
  return c + __half2float(__low2half(ha)) * __half2float(__low2half(hb))
           + __half2float(__high2half(ha)) * __half2float(__high2half(hb));
#endif
}

// Cross-lane add via DPP quad_perm (pure VALU — no LDS pipe):
// CTRL 0xB1 = quad_perm [1,0,3,2] (lane^1).
template <int CTRL>
__device__ __forceinline__ float dpp_xor_add(float x) {
  const int yi = __builtin_amdgcn_mov_dpp(__builtin_bit_cast(int, x),
                                          CTRL, 0xF, 0xF, true);
  return x + __builtin_bit_cast(float, yi);
}

__device__ __forceinline__ unsigned int pack2(float x, float y) {
  __half2 h = __floats2half2_rn(x, y);
  return __builtin_bit_cast(unsigned int, h);
}

__device__ __forceinline__ float fexp2(float x) {
#if __has_builtin(__builtin_amdgcn_exp2f)
  return __builtin_amdgcn_exp2f(x);
#else
  return exp2f(x);
#endif
}
__device__ __forceinline__ float frcp(float x) {
#if __has_builtin(__builtin_amdgcn_rcpf)
  return __builtin_amdgcn_rcpf(x);
#else
  return 1.f / x;
#endif
}

// lgkmcnt-only barrier: LDS ordering without draining global loads/stores.
__device__ __forceinline__ void scan_barrier() {
  asm volatile("s_waitcnt lgkmcnt(0)" ::: "memory");
  __builtin_amdgcn_s_barrier();
  asm volatile("" ::: "memory");
}

__device__ __forceinline__ void barrier_lds() {
  asm volatile("s_waitcnt lgkmcnt(0)" ::: "memory");
  __builtin_amdgcn_s_barrier();
  asm volatile("" ::: "memory");
}

__device__ __forceinline__ void wave_lds_fence() {
  asm volatile("s_waitcnt lgkmcnt(0)" ::: "memory");
}

// ---------------------------------------------------------------------------
// Kernel 1: gi[r, j] = f16( b_ih[j] + (j<256 ? b_hh[j] : 0) + dot(x,w_ih[j]) )
// b_hh fold legal ONLY for r,z rows (b_hn stays under r in the scan).
// Dots via v_pk_fma_f16; f16-accum absmax impact ≈ +0.001 (R8 vs R9).
// ---------------------------------------------------------------------------
__global__ __launch_bounds__(384, 1) void gi_gemm(
    const float* __restrict__ x, const float* __restrict__ w_ih,
    const float* __restrict__ b_ih, const float* __restrict__ b_hh,
    __half* __restrict__ gi) {
  const int j = threadIdx.x;             // 0..383 : output gate-row
  const int rbase = blockIdx.x * 128;    // 128 x-rows per block

  __half2 wreg[128];                     // 256 halves = w_ih row j
  const float* wrow = w_ih + (size_t)j * DIN;
#pragma unroll
  for (int k = 0; k < 128; ++k) {
    float2 w2 = reinterpret_cast<const float2*>(wrow)[k];
    wreg[k] = __floats2half2_rn(w2.x, w2.y);
  }
  const float bias = b_ih[j] + ((j < 256) ? b_hh[j] : 0.f);
  const __half2 z2h = __floats2half2_rn(0.f, 0.f);

  __shared__ alignas(16) unsigned int xs[16 * 128];  // 16 rows x 256 halves

  for (int c = 0; c < 8; ++c) {          // 8 chunks of 16 rows
    barrier_lds();                       // protect xs vs previous chunk reads
    const int row0 = rbase + c * 16;
    for (int i = j; i < 16 * 128; i += 384) {
      const int r = i >> 7, col = i & 127;
      float2 v = reinterpret_cast<const float2*>(x + (size_t)(row0 + r) * DIN)[col];
      xs[i] = pack2(v.x, v.y);
    }
    barrier_lds();
    for (int r = 0; r < 16; ++r) {
      __half2 a0 = z2h, a1 = z2h, a2 = z2h, a3 = z2h;
      const uint4* hp = reinterpret_cast<const uint4*>(xs + r * 128);
#pragma unroll
      for (int k = 0; k < 32; ++k) {
        uint4 hv = hp[k];                // uniform addr -> LDS broadcast
        a0 = __hfma2(wreg[4 * k + 0], __builtin_bit_cast(__half2, hv.x), a0);
        a1 = __hfma2(wreg[4 * k + 1], __builtin_bit_cast(__half2, hv.y), a1);
        a2 = __hfma2(wreg[4 * k + 2], __builtin_bit_cast(__half2, hv.z), a2);
        a3 = __hfma2(wreg[4 * k + 3], __builtin_bit_cast(__half2, hv.w), a3);
      }
      const __half2 s2 = __hadd2(__hadd2(a0, a1), __hadd2(a2, a3));
      const float acc = bias + __low2float(s2) + __high2float(s2);
      gi[(size_t)(row0 + r) * G3 + j] = __float2half(acc);
    }
  }
}

// ---------------------------------------------------------------------------
// Kernel 2: GRU scan, batch-multiplexed waves. 8 blocks x 512 threads:
// waves 0-3 run batch 2*blk, waves 4-7 run batch 2*blk+1 — each SIMD hosts
// one wave of EACH batch (independent dep chains -> while one stalls on LDS
// latency / trans chain, the other issues; the block barrier retires TWO
// timesteps per overhead payment). Per-wave structure identical to R13:
// col c = wl*32 + (l>>1), K-half = l&1, 96 v_pk_fma_f16, one DPP ^1 combine,
// merged gate algebra, h f16 double-buffered (144B stagger), 4-deep prefetch.
// ---------------------------------------------------------------------------
__global__ __launch_bounds__(512, 2) void gru_scan(
    const __half* __restrict__ gi, const float* __restrict__ w_hh,
    const float* __restrict__ b_hh, float* __restrict__ out) {
  const int tid = threadIdx.x;
  const int l   = tid & 63;
  const int bi  = tid >> 8;              // batch slot within block (0/1)
  const int wl  = (tid >> 6) & 3;        // wave role within batch (0..3)
  const int b   = blockIdx.x * 2 + bi;   // global batch
  const int half = l & 1;                // K-half 0/1 (partner = l^1)
  const int c   = wl * 32 + (l >> 1);    // hidden column 0..127

  // Weights: rows {c, 128+c, 256+c}, K-range [half*64, half*64+64), f16x2,
  // prescaled by -log2e (r,z) / -2log2e (n). Same for both batch slots.
  __half2 wgt[3][32];
#pragma unroll
  for (int g = 0; g < 3; ++g) {
    const float sg = (g < 2) ? -SC_RZ : -SC_N;
    const float* row = w_hh + (size_t)(g * H_ + c) * H_ + half * 64;
#pragma unroll
    for (int k = 0; k < 32; ++k) {
      float2 a = reinterpret_cast<const float2*>(row)[k];
      wgt[g][k] = __floats2half2_rn(a.x * sg, a.y * sg);
    }
  }
  // scaled b_hn, folded into the n-acc init of the even lane (once per pair).
  const float bnS = b_hh[2 * H_ + c] * -SC_N;
  const __half2 initN = __floats2half2_rn((half == 0) ? bnS : 0.f, 0.f);
  const __half2 z2h = __floats2half2_rn(0.f, 0.f);

  // h buffers (f16), PER BATCH SLOT: half0 at bytes 0..127, half1 at
  // 144..271 (144 B stagger -> 2 broadcast addrs hit disjoint banks).
  __shared__ alignas(16) char hA[2][288];
  __shared__ alignas(16) char hB[2][288];
  if ((tid & 255) < 72)
    reinterpret_cast<unsigned int*>(hA[bi])[tid & 255] = 0u;  // h0 = 0
  char* const bufA = hA[bi];
  char* const bufB = hB[bi];

  const int abase = half * 144;          // this lane's K-half read base
  const int woff  = (c < 64) ? (c * 2) : (144 + (c - 64) * 2);

  const __half* gp = gi + (size_t)b * T_ * G3;
  float* po = out + ((size_t)b * T_) * H_ + c;
  const int o0 = c, o1 = H_ + c, o2 = 2 * H_ + c;

  // 4-deep prefetch: raw __half regs (convert at use), statically named.
  __half pa0 = gp[o0],          pz0 = gp[o1],          pn0 = gp[o2];
  __half pa1 = gp[G3 + o0],     pz1 = gp[G3 + o1],     pn1 = gp[G3 + o2];
  __half pa2 = gp[2 * G3 + o0], pz2 = gp[2 * G3 + o1], pn2 = gp[2 * G3 + o2];
  __half pa3 = gp[3 * G3 + o0], pz3 = gp[3 * G3 + o1], pn3 = gp[3 * G3 + o2];
  const __half* r0 = gp + 4 * G3;        // refill sources, one per phase
  const __half* r1 = gp + 5 * G3;
  const __half* r2 = gp + 6 * G3;
  const __half* r3 = gp + 7 * G3;

  float hp = 0.f;                        // previous h for col c (f32, exact)
  scan_barrier();

#define STEP(TT, PA, PZ, PN, RB, WB, RP)                                    \
  {                                                                         \
    const float ga = __half2float(PA);                                      \
    const float gz = __half2float(PZ);                                      \
    const float gn = __half2float(PN);                                      \
    if ((TT) + 4 < T_) {  /* refill same named regs for TT+4 */             \
      PA = (RP)[o0]; PZ = (RP)[o1]; PN = (RP)[o2];                          \
    }                                                                       \
    RP += 4 * G3;                                                           \
    __half2 aR0 = z2h, aR1 = z2h;                                           \
    __half2 aZ0 = z2h, aZ1 = z2h;                                           \
    __half2 aN0 = initN, aN1 = z2h;                                         \
    _Pragma("unroll")                                                       \
    for (int k = 0; k < 8; ++k) {                                           \
      const uint4 hv = *reinterpret_cast<const uint4*>((RB) + abase + k * 16);\
      const __half2 hx = __builtin_bit_cast(__half2, hv.x);                 \
      const __half2 hy = __builtin_bit_cast(__half2, hv.y);                 \
      const __half2 hz = __builtin_bit_cast(__half2, hv.z);                 \
      const __half2 hw = __builtin_bit_cast(__half2, hv.w);                 \
      aR0 = __hfma2(wgt[0][4 * k + 0], hx, aR0);                            \
      aR1 = __hfma2(wgt[0][4 * k + 1], hy, aR1);                            \
      aR0 = __hfma2(wgt[0][4 * k + 2], hz, aR0);                            \
      aR1 = __hfma2(wgt[0][4 * k + 3], hw, aR1);                            \
      aZ0 = __hfma2(wgt[1][4 * k + 0], hx, aZ0);                            \
      aZ1 = __hfma2(wgt[1][4 * k + 1], hy, aZ1);                            \
      aZ0 = __hfma2(wgt[1][4 * k + 2], hz, aZ0);                            \
      aZ1 = __hfma2(wgt[1][4 * k + 3], hw, aZ1);                            \
      aN0 = __hfma2(wgt[2][4 * k + 0], hx, aN0);                            \
      aN1 = __hfma2(wgt[2][4 * k + 1], hy, aN1);                            \
      aN0 = __hfma2(wgt[2][4 * k + 2], hz, aN0);                            \
      aN1 = __hfma2(wgt[2][4 * k + 3], hw, aN1);                            \
    }                                                                       \
    const __half2 sR = __hadd2(aR0, aR1);                                   \
    const __half2 sZ = __hadd2(aZ0, aZ1);                                   \
    const __half2 sN = __hadd2(aN0, aN1);                                   \
    const float aRs = __low2float(sR) + __high2float(sR);                   \
    const float aZs = __low2float(sZ) + __high2float(sZ);                   \
    const float aNs = __low2float(sN) + __high2float(sN);                   \
    const float fR = dpp_xor_add<0xB1>(aRs);                                \
    const float fZ = dpp_xor_add<0xB1>(aZs);                                \
    const float fN = dpp_xor_add<0xB1>(aNs);                                \
    const float er = fexp2(fmaf(ga, -SC_RZ, fR));                           \
    const float ez = fexp2(fmaf(gz, -SC_RZ, fZ));  /* parallel with er */   \
    const float rg = frcp(1.f + er);                                        \
    const float en = fexp2(fmaf(gn, -SC_N, rg * fN));                       \
    const float num = fmaf(hp, en, hp) + fmaf(-ez, en, ez);                 \
    const float den = fmaf(ez, en, 1.f + ez + en);                          \
    const float h = num * frcp(den);                                        \
    hp = h;                                                                 \
    if (half == 0) {                                                        \
      po[(size_t)(TT) * H_] = h;                                            \
      *reinterpret_cast<__half*>((WB) + woff) = __float2half(h);            \
    }                                                                       \
    scan_barrier();                                                         \
  }

  for (int t = 0; t < T_; t += 4) {
    STEP(t,     pa0, pz0, pn0, bufA, bufB, r0)
    STEP(t + 1, pa1, pz1, pn1, bufB, bufA, r1)
    STEP(t + 2, pa2, pz2, pn2, bufA, bufB, r2)
    STEP(t + 3, pa3, pz3, pn3, bufB, bufA, r3)
  }
#undef STEP
}

// ---------------------------------------------------------------------------
// Kernel 3: y = h @ w_proj.T + b_proj, then LayerNorm. In-place on io.
// ---------------------------------------------------------------------------
#define PROJ_ROWS 64
__global__ __launch_bounds__(64, 1) void proj_ln(
    float* __restrict__ io, const float* __restrict__ w_proj,
    const float* __restrict__ b_proj, const float* __restrict__ gamma,
    const float* __restrict__ beta) {
  const int lane = threadIdx.x;
  const int row0 = blockIdx.x * PROJ_ROWS;
  const int jA = lane, jB = lane + 64;

  unsigned int wa[64], wb[64];
#pragma unroll
  for (int k = 0; k < 64; ++k) {
    float2 v = reinterpret_cast<const float2*>(w_proj + (size_t)jA * H_)[k];
    wa[k] = pack2(v.x, v.y);
  }
#pragma unroll
  for (int k = 0; k < 64; ++k) {
    float2 v = reinterpret_cast<const float2*>(w_proj + (size_t)jB * H_)[k];
    wb[k] = pack2(v.x, v.y);
  }
  const float bA = b_proj[jA], bB = b_proj[jB];
  const float gmA = gamma[jA], gmB = gamma[jB];
  const float btA = beta[jA], btB = beta[jB];

  __shared__ alignas(16) unsigned int hbuf[64];  // 128 halves: one row

  for (int r = 0; r < PROJ_ROWS; ++r) {
    float* rowp = io + (size_t)(row0 + r) * H_;
    float2 v = reinterpret_cast<float2*>(rowp)[lane];
    hbuf[lane] = pack2(v.x, v.y);
    wave_lds_fence();

    float aA = bA, aB = bB;
    const uint4* hp = reinterpret_cast<const uint4*>(hbuf);
#pragma unroll
    for (int k = 0; k < 16; ++k) {
      uint4 hv = hp[k];
      aA = fdot2(wa[4 * k + 0], hv.x, aA);
      aA = fdot2(wa[4 * k + 1], hv.y, aA);
      aA = fdot2(wa[4 * k + 2], hv.z, aA);
      aA = fdot2(wa[4 * k + 3], hv.w, aA);
      aB = fdot2(wb[4 * k + 0], hv.x, aB);
      aB = fdot2(wb[4 * k + 1], hv.y, aB);
      aB = fdot2(wb[4 * k + 2], hv.z, aB);
      aB = fdot2(wb[4 * k + 3], hv.w, aB);
    }

    float s = aA + aB;
    float q = aA * aA + aB * aB;
#pragma unroll
    for (int m = 1; m < 64; m <<= 1) {
      s += __shfl_xor(s, m, 64);
      q += __shfl_xor(q, m, 64);
    }
    const float mu = s * (1.f / 128.f);
    const float var = q * (1.f / 128.f) - mu * mu;
    const float rs = rsqrtf(var + 1e-5f);
    rowp[lane]      = (aA - mu) * rs * gmA + btA;
    rowp[lane + 64] = (aB - mu) * rs * gmB + btB;
    wave_lds_fence();
  }
}

// ---------------------------------------------------------------------------
extern "C" void kernel_launch(void* const* d_in, const int* in_sizes, int n_in,
                              void* d_out, int out_size, void* d_ws, size_t ws_size,
                              hipStream_t stream) {
  const float* x      = (const float*)d_in[0];
  const float* w_ih   = (const float*)d_in[1];
  const float* w_hh   = (const float*)d_in[2];
  const float* b_ih   = (const float*)d_in[3];
  const float* b_hh   = (const float*)d_in[4];
  const float* w_proj = (const float*)d_in[5];
  const float* b_proj = (const float*)d_in[6];
  const float* gamma  = (const float*)d_in[7];
  const float* beta   = (const float*)d_in[8];

  float* out = (float*)d_out;
  __half* gi = (__half*)d_ws;            // [B*T][384] f16 = 48 MB scratch

  gi_gemm<<<512, 384, 0, stream>>>(x, w_ih, b_ih, b_hh, gi);
  gru_scan<<<B_ / 2, 512, 0, stream>>>(gi, w_hh, b_hh, out);
  proj_ln<<<(B_ * T_) / PROJ_ROWS, 64, 0, stream>>>(out, w_proj, b_proj, gamma, beta);
}

// Round 15
// 1921.976 us; speedup vs baseline: 1.6291x; 1.6291x over previous
//
#include <hip/hip_runtime.h>
#include <hip/hip_fp16.h>

#define B_   16
#define T_   4096
#define DIN  256
#define H_   128
#define G3   384   // 3*H

// exponent prescales: sigmoid -> rcp(1+exp2(-log2e * x)), tanh via sigmoid(2x)
#define SC_RZ 1.4426950408889634f
#define SC_N  2.8853900817779268f

typedef _Float16 half8_t __attribute__((ext_vector_type(8)));
typedef float f32x4 __attribute__((ext_vector_type(4)));

// Cross-lane add via DPP quad_perm (pure VALU — no LDS pipe):
// CTRL 0xB1 = quad_perm [1,0,3,2] (lane^1).
template <int CTRL>
__device__ __forceinline__ float dpp_xor_add(float x) {
  const int yi = __builtin_amdgcn_mov_dpp(__builtin_bit_cast(int, x),
                                          CTRL, 0xF, 0xF, true);
  return x + __builtin_bit_cast(float, yi);
}

__device__ __forceinline__ unsigned int pack2(float x, float y) {
  __half2 h = __floats2half2_rn(x, y);
  return __builtin_bit_cast(unsigned int, h);
}

__device__ __forceinline__ float fexp2(float x) {
#if __has_builtin(__builtin_amdgcn_exp2f)
  return __builtin_amdgcn_exp2f(x);
#else
  return exp2f(x);
#endif
}
__device__ __forceinline__ float frcp(float x) {
#if __has_builtin(__builtin_amdgcn_rcpf)
  return __builtin_amdgcn_rcpf(x);
#else
  return 1.f / x;
#endif
}

// lgkmcnt-only barrier: LDS ordering without draining global loads/stores.
__device__ __forceinline__ void scan_barrier() {
  asm volatile("s_waitcnt lgkmcnt(0)" ::: "memory");
  __builtin_amdgcn_s_barrier();
  asm volatile("" ::: "memory");
}

__device__ __forceinline__ void barrier_lds() {
  asm volatile("s_waitcnt lgkmcnt(0)" ::: "memory");
  __builtin_amdgcn_s_barrier();
  asm volatile("" ::: "memory");
}

__device__ __forceinline__ void wave_lds_fence() {
  asm volatile("s_waitcnt lgkmcnt(0)" ::: "memory");
}

// ---------------------------------------------------------------------------
// Kernel 1 (MFMA): gi[r, n] = f16( b_ih[n] + (n<256 ? b_hh[n] : 0)
//                                  + dot(x[r,:], w_ih[n,:]) )
// C = X(f16) @ W^T via mfma_f32_16x16x32_f16. Fragment mappings verified on
// HW by R4's passing MFMA scan: A lane l: row=l&15, k=(l>>4)*8+e;
// B lane l: col=l&15, k=(l>>4)*8+e; D: col=l&15, row=(l>>4)*4+reg.
// 256 blocks x 512 threads (8 waves). Wave wv owns cols [wv*48, wv*48+48)
// (3 col-tiles); W-frags in registers (96 VGPR). Block covers 256 rows in
// 16 strips of 16; x staged per strip into swizzled LDS f16 (^((row&7)<<4),
// R4-proven conflict-free).
// ---------------------------------------------------------------------------
__global__ __launch_bounds__(512, 1) void gi_gemm(
    const float* __restrict__ x, const float* __restrict__ w_ih,
    const float* __restrict__ b_ih, const float* __restrict__ b_hh,
    __half* __restrict__ gi) {
  const int tid = threadIdx.x;
  const int l   = tid & 63;
  const int wv  = tid >> 6;            // wave 0..7
  const int l15 = l & 15;
  const int g4  = l >> 4;              // 0..3
  const int rbase = blockIdx.x * 256;

  // B fragments + bias per col-tile
  half8_t wf[3][8];
  float bias[3];
#pragma unroll
  for (int ct = 0; ct < 3; ++ct) {
    const int n = wv * 48 + ct * 16 + l15;
    const float* wrow = w_ih + (size_t)n * DIN;
#pragma unroll
    for (int kt = 0; kt < 8; ++kt) {
      const float* p = wrow + kt * 32 + g4 * 8;
      const float4 lo = *reinterpret_cast<const float4*>(p);
      const float4 hi = *reinterpret_cast<const float4*>(p + 4);
      half8_t f;
      f[0] = (_Float16)lo.x; f[1] = (_Float16)lo.y;
      f[2] = (_Float16)lo.z; f[3] = (_Float16)lo.w;
      f[4] = (_Float16)hi.x; f[5] = (_Float16)hi.y;
      f[6] = (_Float16)hi.z; f[7] = (_Float16)hi.w;
      wf[ct][kt] = f;
    }
    bias[ct] = b_ih[n] + ((n < 256) ? b_hh[n] : 0.f);
  }

  __shared__ alignas(16) char xbuf[16 * 512];  // 16 rows x 256 f16, swizzled

  const int srow = tid >> 5;           // staging row 0..15
  const int kseg = tid & 31;           // 8-float segment 0..31
  const int wofs = srow * 512 + ((kseg * 16) ^ ((srow & 7) << 4));

  int aoff[8];
#pragma unroll
  for (int kt = 0; kt < 8; ++kt)
    aoff[kt] = l15 * 512 + ((kt * 64 + g4 * 16) ^ ((l15 & 7) << 4));

  for (int s = 0; s < 16; ++s) {
    barrier_lds();                     // WAR: prev strip's A-reads done
    {
      const float* src = x + (size_t)(rbase + s * 16 + srow) * DIN + kseg * 8;
      const float4 lo = *reinterpret_cast<const float4*>(src);
      const float4 hi = *reinterpret_cast<const float4*>(src + 4);
      half8_t f;
      f[0] = (_Float16)lo.x; f[1] = (_Float16)lo.y;
      f[2] = (_Float16)lo.z; f[3] = (_Float16)lo.w;
      f[4] = (_Float16)hi.x; f[5] = (_Float16)hi.y;
      f[6] = (_Float16)hi.z; f[7] = (_Float16)hi.w;
      *reinterpret_cast<half8_t*>(xbuf + wofs) = f;
    }
    barrier_lds();                     // RAW: staging visible

    f32x4 acc0 = {bias[0], bias[0], bias[0], bias[0]};
    f32x4 acc1 = {bias[1], bias[1], bias[1], bias[1]};
    f32x4 acc2 = {bias[2], bias[2], bias[2], bias[2]};
#pragma unroll
    for (int kt = 0; kt < 8; ++kt) {
      const half8_t a = *reinterpret_cast<const half8_t*>(xbuf + aoff[kt]);
      acc0 = __builtin_amdgcn_mfma_f32_16x16x32_f16(a, wf[0][kt], acc0, 0, 0, 0);
      acc1 = __builtin_amdgcn_mfma_f32_16x16x32_f16(a, wf[1][kt], acc1, 0, 0, 0);
      acc2 = __builtin_amdgcn_mfma_f32_16x16x32_f16(a, wf[2][kt], acc2, 0, 0, 0);
    }

    const size_t r0 = (size_t)(rbase + s * 16 + g4 * 4);
#pragma unroll
    for (int i = 0; i < 4; ++i) {
      __half* dst = gi + (r0 + i) * G3 + wv * 48 + l15;
      dst[0]  = __float2half(acc0[i]);
      dst[16] = __float2half(acc1[i]);
      dst[32] = __float2half(acc2[i]);
    }
  }
}

// ---------------------------------------------------------------------------
// Kernel 2: GRU scan — byte-identical to R13 (proven 1809 us, absmax .03125).
// 16 blocks (1/batch) x 256 threads (4 waves, 1/SIMD). col c = w*32 + (l>>1),
// K-half = l&1; 96 v_pk_fma_f16; ONE DPP ^1 combine; merged gate algebra;
// h f16 double-buffered LDS (144B stagger); 4-deep gi prefetch.
// ---------------------------------------------------------------------------
__global__ __launch_bounds__(256, 1) void gru_scan(
    const __half* __restrict__ gi, const float* __restrict__ w_hh,
    const float* __restrict__ b_hh, float* __restrict__ out) {
  const int b   = blockIdx.x;
  const int tid = threadIdx.x;
  const int l   = tid & 63;
  const int w   = tid >> 6;              // wave 0..3
  const int half = l & 1;                // K-half 0/1 (partner = l^1)
  const int c   = w * 32 + (l >> 1);     // hidden column 0..127

  __half2 wgt[3][32];
#pragma unroll
  for (int g = 0; g < 3; ++g) {
    const float sg = (g < 2) ? -SC_RZ : -SC_N;
    const float* row = w_hh + (size_t)(g * H_ + c) * H_ + half * 64;
#pragma unroll
    for (int k = 0; k < 32; ++k) {
      float2 a = reinterpret_cast<const float2*>(row)[k];
      wgt[g][k] = __floats2half2_rn(a.x * sg, a.y * sg);
    }
  }
  const float bnS = b_hh[2 * H_ + c] * -SC_N;
  const __half2 initN = __floats2half2_rn((half == 0) ? bnS : 0.f, 0.f);
  const __half2 z2h = __floats2half2_rn(0.f, 0.f);

  __shared__ alignas(16) char hA[288];
  __shared__ alignas(16) char hB[288];
  if (tid < 72) reinterpret_cast<unsigned int*>(hA)[tid] = 0u;  // h0 = 0

  const int abase = half * 144;
  const int woff  = (c < 64) ? (c * 2) : (144 + (c - 64) * 2);

  const __half* gp = gi + (size_t)b * T_ * G3;
  float* po = out + ((size_t)b * T_) * H_ + c;
  const int o0 = c, o1 = H_ + c, o2 = 2 * H_ + c;

  __half pa0 = gp[o0],          pz0 = gp[o1],          pn0 = gp[o2];
  __half pa1 = gp[G3 + o0],     pz1 = gp[G3 + o1],     pn1 = gp[G3 + o2];
  __half pa2 = gp[2 * G3 + o0], pz2 = gp[2 * G3 + o1], pn2 = gp[2 * G3 + o2];
  __half pa3 = gp[3 * G3 + o0], pz3 = gp[3 * G3 + o1], pn3 = gp[3 * G3 + o2];
  const __half* r0 = gp + 4 * G3;
  const __half* r1 = gp + 5 * G3;
  const __half* r2 = gp + 6 * G3;
  const __half* r3 = gp + 7 * G3;

  float hp = 0.f;
  scan_barrier();

#define STEP(TT, PA, PZ, PN, RB, WB, RP)                                    \
  {                                                                         \
    const float ga = __half2float(PA);                                      \
    const float gz = __half2float(PZ);                                      \
    const float gn = __half2float(PN);                                      \
    if ((TT) + 4 < T_) {                                                    \
      PA = (RP)[o0]; PZ = (RP)[o1]; PN = (RP)[o2];                          \
    }                                                                       \
    RP += 4 * G3;                                                           \
    __half2 aR0 = z2h, aR1 = z2h;                                           \
    __half2 aZ0 = z2h, aZ1 = z2h;                                           \
    __half2 aN0 = initN, aN1 = z2h;                                         \
    _Pragma("unroll")                                                       \
    for (int k = 0; k < 8; ++k) {                                           \
      const uint4 hv = *reinterpret_cast<const uint4*>((RB) + abase + k * 16);\
      const __half2 hx = __builtin_bit_cast(__half2, hv.x);                 \
      const __half2 hy = __builtin_bit_cast(__half2, hv.y);                 \
      const __half2 hz = __builtin_bit_cast(__half2, hv.z);                 \
      const __half2 hw = __builtin_bit_cast(__half2, hv.w);                 \
      aR0 = __hfma2(wgt[0][4 * k + 0], hx, aR0);                            \
      aR1 = __hfma2(wgt[0][4 * k + 1], hy, aR1);                            \
      aR0 = __hfma2(wgt[0][4 * k + 2], hz, aR0);                            \
      aR1 = __hfma2(wgt[0][4 * k + 3], hw, aR1);                            \
      aZ0 = __hfma2(wgt[1][4 * k + 0], hx, aZ0);                            \
      aZ1 = __hfma2(wgt[1][4 * k + 1], hy, aZ1);                            \
      aZ0 = __hfma2(wgt[1][4 * k + 2], hz, aZ0);                            \
      aZ1 = __hfma2(wgt[1][4 * k + 3], hw, aZ1);                            \
      aN0 = __hfma2(wgt[2][4 * k + 0], hx, aN0);                            \
      aN1 = __hfma2(wgt[2][4 * k + 1], hy, aN1);                            \
      aN0 = __hfma2(wgt[2][4 * k + 2], hz, aN0);                            \
      aN1 = __hfma2(wgt[2][4 * k + 3], hw, aN1);                            \
    }                                                                       \
    const __half2 sR = __hadd2(aR0, aR1);                                   \
    const __half2 sZ = __hadd2(aZ0, aZ1);                                   \
    const __half2 sN = __hadd2(aN0, aN1);                                   \
    const float aRs = __low2float(sR) + __high2float(sR);                   \
    const float aZs = __low2float(sZ) + __high2float(sZ);                   \
    const float aNs = __low2float(sN) + __high2float(sN);                   \
    const float fR = dpp_xor_add<0xB1>(aRs);                                \
    const float fZ = dpp_xor_add<0xB1>(aZs);                                \
    const float fN = dpp_xor_add<0xB1>(aNs);                                \
    const float er = fexp2(fmaf(ga, -SC_RZ, fR));                           \
    const float ez = fexp2(fmaf(gz, -SC_RZ, fZ));                           \
    const float rg = frcp(1.f + er);                                        \
    const float en = fexp2(fmaf(gn, -SC_N, rg * fN));                       \
    const float num = fmaf(hp, en, hp) + fmaf(-ez, en, ez);                 \
    const float den = fmaf(ez, en, 1.f + ez + en);                          \
    const float h = num * frcp(den);                                        \
    hp = h;                                                                 \
    if (half == 0) {                                                        \
      po[(size_t)(TT) * H_] = h;                                            \
      *reinterpret_cast<__half*>((WB) + woff) = __float2half(h);            \
    }                                                                       \
    scan_barrier();                                                         \
  }

  for (int t = 0; t < T_; t += 4) {
    STEP(t,     pa0, pz0, pn0, hA, hB, r0)
    STEP(t + 1, pa1, pz1, pn1, hB, hA, r1)
    STEP(t + 2, pa2, pz2, pn2, hA, hB, r2)
    STEP(t + 3, pa3, pz3, pn3, hB, hA, r3)
  }
#undef STEP
}

// ---------------------------------------------------------------------------
// Kernel 3: y = h @ w_proj.T + b_proj, then LayerNorm. In-place on io.
// Inner dots via v_pk_fma_f16 (2 cyc vs fdot2's ~6); LN stats in f32.
// ---------------------------------------------------------------------------
#define PROJ_ROWS 64
__global__ __launch_bounds__(64, 1) void proj_ln(
    float* __restrict__ io, const float* __restrict__ w_proj,
    const float* __restrict__ b_proj, const float* __restrict__ gamma,
    const float* __restrict__ beta) {
  const int lane = threadIdx.x;
  const int row0 = blockIdx.x * PROJ_ROWS;
  const int jA = lane, jB = lane + 64;

  __half2 wa2[64], wb2[64];
#pragma unroll
  for (int k = 0; k < 64; ++k) {
    float2 v = reinterpret_cast<const float2*>(w_proj + (size_t)jA * H_)[k];
    wa2[k] = __floats2half2_rn(v.x, v.y);
  }
#pragma unroll
  for (int k = 0; k < 64; ++k) {
    float2 v = reinterpret_cast<const float2*>(w_proj + (size_t)jB * H_)[k];
    wb2[k] = __floats2half2_rn(v.x, v.y);
  }
  const float bA = b_proj[jA], bB = b_proj[jB];
  const float gmA = gamma[jA], gmB = gamma[jB];
  const float btA = beta[jA], btB = beta[jB];
  const __half2 z2h = __floats2half2_rn(0.f, 0.f);

  __shared__ alignas(16) unsigned int hbuf[64];  // 128 halves: one row

  for (int r = 0; r < PROJ_ROWS; ++r) {
    float* rowp = io + (size_t)(row0 + r) * H_;
    float2 v = reinterpret_cast<float2*>(rowp)[lane];
    hbuf[lane] = pack2(v.x, v.y);
    wave_lds_fence();

    __half2 A0 = z2h, A1 = z2h, A2 = z2h, A3 = z2h;
    __half2 B0 = z2h, B1 = z2h, B2 = z2h, B3 = z2h;
    const uint4* hp = reinterpret_cast<const uint4*>(hbuf);
#pragma unroll
    for (int k = 0; k < 16; ++k) {
      const uint4 hv = hp[k];
      const __half2 hx = __builtin_bit_cast(__half2, hv.x);
      const __half2 hy = __builtin_bit_cast(__half2, hv.y);
      const __half2 hz = __builtin_bit_cast(__half2, hv.z);
      const __half2 hw = __builtin_bit_cast(__half2, hv.w);
      A0 = __hfma2(wa2[4 * k + 0], hx, A0);
      A1 = __hfma2(wa2[4 * k + 1], hy, A1);
      A2 = __hfma2(wa2[4 * k + 2], hz, A2);
      A3 = __hfma2(wa2[4 * k + 3], hw, A3);
      B0 = __hfma2(wb2[4 * k + 0], hx, B0);
      B1 = __hfma2(wb2[4 * k + 1], hy, B1);
      B2 = __hfma2(wb2[4 * k + 2], hz, B2);
      B3 = __hfma2(wb2[4 * k + 3], hw, B3);
    }
    const __half2 sA = __hadd2(__hadd2(A0, A1), __hadd2(A2, A3));
    const __half2 sB = __hadd2(__hadd2(B0, B1), __hadd2(B2, B3));
    const float aA = bA + __low2float(sA) + __high2float(sA);
    const float aB = bB + __low2float(sB) + __high2float(sB);

    float s = aA + aB;
    float q = aA * aA + aB * aB;
#pragma unroll
    for (int m = 1; m < 64; m <<= 1) {
      s += __shfl_xor(s, m, 64);
      q += __shfl_xor(q, m, 64);
    }
    const float mu = s * (1.f / 128.f);
    const float var = q * (1.f / 128.f) - mu * mu;
    const float rs = rsqrtf(var + 1e-5f);
    rowp[lane]      = (aA - mu) * rs * gmA + btA;
    rowp[lane + 64] = (aB - mu) * rs * gmB + btB;
    wave_lds_fence();
  }
}

// ---------------------------------------------------------------------------
extern "C" void kernel_launch(void* const* d_in, const int* in_sizes, int n_in,
                              void* d_out, int out_size, void* d_ws, size_t ws_size,
                              hipStream_t stream) {
  const float* x      = (const float*)d_in[0];
  const float* w_ih   = (const float*)d_in[1];
  const float* w_hh   = (const float*)d_in[2];
  const float* b_ih   = (const float*)d_in[3];
  const float* b_hh   = (const float*)d_in[4];
  const float* w_proj = (const float*)d_in[5];
  const float* b_proj = (const float*)d_in[6];
  const float* gamma  = (const float*)d_in[7];
  const float* beta   = (const float*)d_in[8];

  float* out = (float*)d_out;
  __half* gi = (__half*)d_ws;            // [B*T][384] f16 = 48 MB scratch

  gi_gemm<<<256, 512, 0, stream>>>(x, w_ih, b_ih, b_hh, gi);
  gru_scan<<<B_, 256, 0, stream>>>(gi, w_hh, b_hh, out);
  proj_ln<<<(B_ * T_) / PROJ_ROWS, 64, 0, stream>>>(out, w_proj, b_proj, gamma, beta);
}

// Round 16
// 1901.057 us; speedup vs baseline: 1.6471x; 1.0110x over previous
//
#include <hip/hip_runtime.h>
#include <hip/hip_fp16.h>

#define B_   16
#define T_   4096
#define DIN  256
#define H_   128
#define G3   384   // 3*H

// exponent prescales: sigmoid -> rcp(1+exp2(-log2e * x)), tanh via sigmoid(2x)
#define SC_RZ 1.4426950408889634f
#define SC_N  2.8853900817779268f

typedef _Float16 half2_t __attribute__((ext_vector_type(2)));
typedef _Float16 half8_t __attribute__((ext_vector_type(8)));
typedef float f32x4 __attribute__((ext_vector_type(4)));

// f32 <- low(a)*low(b) + high(a)*high(b) + c   (f16 inputs, f32 accumulate)
__device__ __forceinline__ float fdot2h(__half2 a, __half2 b, float c) {
#if __has_builtin(__builtin_amdgcn_fdot2)
  return __builtin_amdgcn_fdot2(__builtin_bit_cast(half2_t, a),
                                __builtin_bit_cast(half2_t, b), c, false);
#else
  return c + __low2float(a) * __low2float(b) +
         __high2float(a) * __high2float(b);
#endif
}

// Cross-lane add via DPP quad_perm (pure VALU — no LDS pipe):
// CTRL 0xB1 = quad_perm [1,0,3,2] (lane^1).
template <int CTRL>
__device__ __forceinline__ float dpp_xor_add(float x) {
  const int yi = __builtin_amdgcn_mov_dpp(__builtin_bit_cast(int, x),
                                          CTRL, 0xF, 0xF, true);
  return x + __builtin_bit_cast(float, yi);
}

__device__ __forceinline__ unsigned int pack2(float x, float y) {
  __half2 h = __floats2half2_rn(x, y);
  return __builtin_bit_cast(unsigned int, h);
}

__device__ __forceinline__ float fexp2(float x) {
#if __has_builtin(__builtin_amdgcn_exp2f)
  return __builtin_amdgcn_exp2f(x);
#else
  return exp2f(x);
#endif
}
__device__ __forceinline__ float frcp(float x) {
#if __has_builtin(__builtin_amdgcn_rcpf)
  return __builtin_amdgcn_rcpf(x);
#else
  return 1.f / x;
#endif
}

// lgkmcnt-only barrier: LDS ordering without draining global loads/stores.
__device__ __forceinline__ void scan_barrier() {
  asm volatile("s_waitcnt lgkmcnt(0)" ::: "memory");
  __builtin_amdgcn_s_barrier();
  asm volatile("" ::: "memory");
}

__device__ __forceinline__ void barrier_lds() {
  asm volatile("s_waitcnt lgkmcnt(0)" ::: "memory");
  __builtin_amdgcn_s_barrier();
  asm volatile("" ::: "memory");
}

__device__ __forceinline__ void wave_lds_fence() {
  asm volatile("s_waitcnt lgkmcnt(0)" ::: "memory");
}

// ---------------------------------------------------------------------------
// Kernel 1 (MFMA): gi[r, n] = f16( b_ih[n] + (n<256 ? b_hh[n] : 0)
//                                  + dot(x[r,:], w_ih[n,:]) )
// (R15-proven, unchanged.)
// ---------------------------------------------------------------------------
__global__ __launch_bounds__(512, 1) void gi_gemm(
    const float* __restrict__ x, const float* __restrict__ w_ih,
    const float* __restrict__ b_ih, const float* __restrict__ b_hh,
    __half* __restrict__ gi) {
  const int tid = threadIdx.x;
  const int l   = tid & 63;
  const int wv  = tid >> 6;            // wave 0..7
  const int l15 = l & 15;
  const int g4  = l >> 4;              // 0..3
  const int rbase = blockIdx.x * 256;

  half8_t wf[3][8];
  float bias[3];
#pragma unroll
  for (int ct = 0; ct < 3; ++ct) {
    const int n = wv * 48 + ct * 16 + l15;
    const float* wrow = w_ih + (size_t)n * DIN;
#pragma unroll
    for (int kt = 0; kt < 8; ++kt) {
      const float* p = wrow + kt * 32 + g4 * 8;
      const float4 lo = *reinterpret_cast<const float4*>(p);
      const float4 hi = *reinterpret_cast<const float4*>(p + 4);
      half8_t f;
      f[0] = (_Float16)lo.x; f[1] = (_Float16)lo.y;
      f[2] = (_Float16)lo.z; f[3] = (_Float16)lo.w;
      f[4] = (_Float16)hi.x; f[5] = (_Float16)hi.y;
      f[6] = (_Float16)hi.z; f[7] = (_Float16)hi.w;
      wf[ct][kt] = f;
    }
    bias[ct] = b_ih[n] + ((n < 256) ? b_hh[n] : 0.f);
  }

  __shared__ alignas(16) char xbuf[16 * 512];  // 16 rows x 256 f16, swizzled

  const int srow = tid >> 5;           // staging row 0..15
  const int kseg = tid & 31;           // 8-float segment 0..31
  const int wofs = srow * 512 + ((kseg * 16) ^ ((srow & 7) << 4));

  int aoff[8];
#pragma unroll
  for (int kt = 0; kt < 8; ++kt)
    aoff[kt] = l15 * 512 + ((kt * 64 + g4 * 16) ^ ((l15 & 7) << 4));

  for (int s = 0; s < 16; ++s) {
    barrier_lds();                     // WAR: prev strip's A-reads done
    {
      const float* src = x + (size_t)(rbase + s * 16 + srow) * DIN + kseg * 8;
      const float4 lo = *reinterpret_cast<const float4*>(src);
      const float4 hi = *reinterpret_cast<const float4*>(src + 4);
      half8_t f;
      f[0] = (_Float16)lo.x; f[1] = (_Float16)lo.y;
      f[2] = (_Float16)lo.z; f[3] = (_Float16)lo.w;
      f[4] = (_Float16)hi.x; f[5] = (_Float16)hi.y;
      f[6] = (_Float16)hi.z; f[7] = (_Float16)hi.w;
      *reinterpret_cast<half8_t*>(xbuf + wofs) = f;
    }
    barrier_lds();                     // RAW: staging visible

    f32x4 acc0 = {bias[0], bias[0], bias[0], bias[0]};
    f32x4 acc1 = {bias[1], bias[1], bias[1], bias[1]};
    f32x4 acc2 = {bias[2], bias[2], bias[2], bias[2]};
#pragma unroll
    for (int kt = 0; kt < 8; ++kt) {
      const half8_t a = *reinterpret_cast<const half8_t*>(xbuf + aoff[kt]);
      acc0 = __builtin_amdgcn_mfma_f32_16x16x32_f16(a, wf[0][kt], acc0, 0, 0, 0);
      acc1 = __builtin_amdgcn_mfma_f32_16x16x32_f16(a, wf[1][kt], acc1, 0, 0, 0);
      acc2 = __builtin_amdgcn_mfma_f32_16x16x32_f16(a, wf[2][kt], acc2, 0, 0, 0);
    }

    const size_t r0 = (size_t)(rbase + s * 16 + g4 * 4);
#pragma unroll
    for (int i = 0; i < 4; ++i) {
      __half* dst = gi + (r0 + i) * G3 + wv * 48 + l15;
      dst[0]  = __float2half(acc0[i]);
      dst[16] = __float2half(acc1[i]);
      dst[32] = __float2half(acc2[i]);
    }
  }
}

// ---------------------------------------------------------------------------
// Kernel 2: GRU scan — R13 structure with shortened reduction chain:
// fdot2(·,(1,1),0) horizontal combine (replaces 2 cvt + add per gate) and
// gnS precomputed off-chain so en = exp2(fmaf(rg, fN, gnS)).
// 16 blocks (1/batch) x 256 threads (4 waves, 1/SIMD). col c = w*32 + (l>>1),
// K-half = l&1; 96 v_pk_fma_f16; ONE DPP ^1 combine; merged gate algebra;
// h f16 double-buffered LDS (144B stagger); 4-deep gi prefetch.
// ---------------------------------------------------------------------------
__global__ __launch_bounds__(256, 1) void gru_scan(
    const __half* __restrict__ gi, const float* __restrict__ w_hh,
    const float* __restrict__ b_hh, float* __restrict__ out) {
  const int b   = blockIdx.x;
  const int tid = threadIdx.x;
  const int l   = tid & 63;
  const int w   = tid >> 6;              // wave 0..3
  const int half = l & 1;                // K-half 0/1 (partner = l^1)
  const int c   = w * 32 + (l >> 1);     // hidden column 0..127

  __half2 wgt[3][32];
#pragma unroll
  for (int g = 0; g < 3; ++g) {
    const float sg = (g < 2) ? -SC_RZ : -SC_N;
    const float* row = w_hh + (size_t)(g * H_ + c) * H_ + half * 64;
#pragma unroll
    for (int k = 0; k < 32; ++k) {
      float2 a = reinterpret_cast<const float2*>(row)[k];
      wgt[g][k] = __floats2half2_rn(a.x * sg, a.y * sg);
    }
  }
  const float bnS = b_hh[2 * H_ + c] * -SC_N;
  const __half2 initN = __floats2half2_rn((half == 0) ? bnS : 0.f, 0.f);
  const __half2 z2h = __floats2half2_rn(0.f, 0.f);
  const __half2 one2 = __floats2half2_rn(1.f, 1.f);

  __shared__ alignas(16) char hA[288];
  __shared__ alignas(16) char hB[288];
  if (tid < 72) reinterpret_cast<unsigned int*>(hA)[tid] = 0u;  // h0 = 0

  const int abase = half * 144;
  const int woff  = (c < 64) ? (c * 2) : (144 + (c - 64) * 2);

  const __half* gp = gi + (size_t)b * T_ * G3;
  float* po = out + ((size_t)b * T_) * H_ + c;
  const int o0 = c, o1 = H_ + c, o2 = 2 * H_ + c;

  __half pa0 = gp[o0],          pz0 = gp[o1],          pn0 = gp[o2];
  __half pa1 = gp[G3 + o0],     pz1 = gp[G3 + o1],     pn1 = gp[G3 + o2];
  __half pa2 = gp[2 * G3 + o0], pz2 = gp[2 * G3 + o1], pn2 = gp[2 * G3 + o2];
  __half pa3 = gp[3 * G3 + o0], pz3 = gp[3 * G3 + o1], pn3 = gp[3 * G3 + o2];
  const __half* r0 = gp + 4 * G3;
  const __half* r1 = gp + 5 * G3;
  const __half* r2 = gp + 6 * G3;
  const __half* r3 = gp + 7 * G3;

  float hp = 0.f;
  scan_barrier();

#define STEP(TT, PA, PZ, PN, RB, WB, RP)                                    \
  {                                                                         \
    const float ga = __half2float(PA);                                      \
    const float gz = __half2float(PZ);                                      \
    const float gnS = __half2float(PN) * -SC_N;  /* off critical chain */   \
    if ((TT) + 4 < T_) {                                                    \
      PA = (RP)[o0]; PZ = (RP)[o1]; PN = (RP)[o2];                          \
    }                                                                       \
    RP += 4 * G3;                                                           \
    __half2 aR0 = z2h, aR1 = z2h;                                           \
    __half2 aZ0 = z2h, aZ1 = z2h;                                           \
    __half2 aN0 = initN, aN1 = z2h;                                         \
    _Pragma("unroll")                                                       \
    for (int k = 0; k < 8; ++k) {                                           \
      const uint4 hv = *reinterpret_cast<const uint4*>((RB) + abase + k * 16);\
      const __half2 hx = __builtin_bit_cast(__half2, hv.x);                 \
      const __half2 hy = __builtin_bit_cast(__half2, hv.y);                 \
      const __half2 hz = __builtin_bit_cast(__half2, hv.z);                 \
      const __half2 hw = __builtin_bit_cast(__half2, hv.w);                 \
      aR0 = __hfma2(wgt[0][4 * k + 0], hx, aR0);                            \
      aR1 = __hfma2(wgt[0][4 * k + 1], hy, aR1);                            \
      aR0 = __hfma2(wgt[0][4 * k + 2], hz, aR0);                            \
      aR1 = __hfma2(wgt[0][4 * k + 3], hw, aR1);                            \
      aZ0 = __hfma2(wgt[1][4 * k + 0], hx, aZ0);                            \
      aZ1 = __hfma2(wgt[1][4 * k + 1], hy, aZ1);                            \
      aZ0 = __hfma2(wgt[1][4 * k + 2], hz, aZ0);                            \
      aZ1 = __hfma2(wgt[1][4 * k + 3], hw, aZ1);                            \
      aN0 = __hfma2(wgt[2][4 * k + 0], hx, aN0);                            \
      aN1 = __hfma2(wgt[2][4 * k + 1], hy, aN1);                            \
      aN0 = __hfma2(wgt[2][4 * k + 2], hz, aN0);                            \
      aN1 = __hfma2(wgt[2][4 * k + 3], hw, aN1);                            \
    }                                                                       \
    /* horizontal: fdot2 with (1,1) = low+high in ONE f32-accurate op */    \
    const float aRs = fdot2h(__hadd2(aR0, aR1), one2, 0.f);                 \
    const float aZs = fdot2h(__hadd2(aZ0, aZ1), one2, 0.f);                 \
    const float aNs = fdot2h(__hadd2(aN0, aN1), one2, 0.f);                 \
    const float fR = dpp_xor_add<0xB1>(aRs);                                \
    const float fZ = dpp_xor_add<0xB1>(aZs);                                \
    const float fN = dpp_xor_add<0xB1>(aNs);                                \
    const float er = fexp2(fmaf(ga, -SC_RZ, fR));                           \
    const float ez = fexp2(fmaf(gz, -SC_RZ, fZ));  /* parallel with er */   \
    const float rg = frcp(1.f + er);                                        \
    const float en = fexp2(fmaf(rg, fN, gnS));                              \
    const float num = fmaf(hp, en, hp) + fmaf(-ez, en, ez);                 \
    const float den = fmaf(ez, en, 1.f + ez + en);                          \
    const float h = num * frcp(den);                                        \
    hp = h;                                                                 \
    if (half == 0) {                                                        \
      po[(size_t)(TT) * H_] = h;                                            \
      *reinterpret_cast<__half*>((WB) + woff) = __float2half(h);            \
    }                                                                       \
    scan_barrier();                                                         \
  }

  for (int t = 0; t < T_; t += 4) {
    STEP(t,     pa0, pz0, pn0, hA, hB, r0)
    STEP(t + 1, pa1, pz1, pn1, hB, hA, r1)
    STEP(t + 2, pa2, pz2, pn2, hA, hB, r2)
    STEP(t + 3, pa3, pz3, pn3, hB, hA, r3)
  }
#undef STEP
}

// ---------------------------------------------------------------------------
// Kernel 3: y = h @ w_proj.T + b_proj, then LayerNorm. In-place on io.
// (R15-proven, unchanged.)
// ---------------------------------------------------------------------------
#define PROJ_ROWS 64
__global__ __launch_bounds__(64, 1) void proj_ln(
    float* __restrict__ io, const float* __restrict__ w_proj,
    const float* __restrict__ b_proj, const float* __restrict__ gamma,
    const float* __restrict__ beta) {
  const int lane = threadIdx.x;
  const int row0 = blockIdx.x * PROJ_ROWS;
  const int jA = lane, jB = lane + 64;

  __half2 wa2[64], wb2[64];
#pragma unroll
  for (int k = 0; k < 64; ++k) {
    float2 v = reinterpret_cast<const float2*>(w_proj + (size_t)jA * H_)[k];
    wa2[k] = __floats2half2_rn(v.x, v.y);
  }
#pragma unroll
  for (int k = 0; k < 64; ++k) {
    float2 v = reinterpret_cast<const float2*>(w_proj + (size_t)jB * H_)[k];
    wb2[k] = __floats2half2_rn(v.x, v.y);
  }
  const float bA = b_proj[jA], bB = b_proj[jB];
  const float gmA = gamma[jA], gmB = gamma[jB];
  const float btA = beta[jA], btB = beta[jB];
  const __half2 z2h = __floats2half2_rn(0.f, 0.f);

  __shared__ alignas(16) unsigned int hbuf[64];  // 128 halves: one row

  for (int r = 0; r < PROJ_ROWS; ++r) {
    float* rowp = io + (size_t)(row0 + r) * H_;
    float2 v = reinterpret_cast<float2*>(rowp)[lane];
    hbuf[lane] = pack2(v.x, v.y);
    wave_lds_fence();

    __half2 A0 = z2h, A1 = z2h, A2 = z2h, A3 = z2h;
    __half2 B0 = z2h, B1 = z2h, B2 = z2h, B3 = z2h;
    const uint4* hp = reinterpret_cast<const uint4*>(hbuf);
#pragma unroll
    for (int k = 0; k < 16; ++k) {
      const uint4 hv = hp[k];
      const __half2 hx = __builtin_bit_cast(__half2, hv.x);
      const __half2 hy = __builtin_bit_cast(__half2, hv.y);
      const __half2 hz = __builtin_bit_cast(__half2, hv.z);
      const __half2 hw = __builtin_bit_cast(__half2, hv.w);
      A0 = __hfma2(wa2[4 * k + 0], hx, A0);
      A1 = __hfma2(wa2[4 * k + 1], hy, A1);
      A2 = __hfma2(wa2[4 * k + 2], hz, A2);
      A3 = __hfma2(wa2[4 * k + 3], hw, A3);
      B0 = __hfma2(wb2[4 * k + 0], hx, B0);
      B1 = __hfma2(wb2[4 * k + 1], hy, B1);
      B2 = __hfma2(wb2[4 * k + 2], hz, B2);
      B3 = __hfma2(wb2[4 * k + 3], hw, B3);
    }
    const __half2 sA = __hadd2(__hadd2(A0, A1), __hadd2(A2, A3));
    const __half2 sB = __hadd2(__hadd2(B0, B1), __hadd2(B2, B3));
    const float aA = bA + __low2float(sA) + __high2float(sA);
    const float aB = bB + __low2float(sB) + __high2float(sB);

    float s = aA + aB;
    float q = aA * aA + aB * aB;
#pragma unroll
    for (int m = 1; m < 64; m <<= 1) {
      s += __shfl_xor(s, m, 64);
      q += __shfl_xor(q, m, 64);
    }
    const float mu = s * (1.f / 128.f);
    const float var = q * (1.f / 128.f) - mu * mu;
    const float rs = rsqrtf(var + 1e-5f);
    rowp[lane]      = (aA - mu) * rs * gmA + btA;
    rowp[lane + 64] = (aB - mu) * rs * gmB + btB;
    wave_lds_fence();
  }
}

// ---------------------------------------------------------------------------
extern "C" void kernel_launch(void* const* d_in, const int* in_sizes, int n_in,
                              void* d_out, int out_size, void* d_ws, size_t ws_size,
                              hipStream_t stream) {
  const float* x      = (const float*)d_in[0];
  const float* w_ih   = (const float*)d_in[1];
  const float* w_hh   = (const float*)d_in[2];
  const float* b_ih   = (const float*)d_in[3];
  const float* b_hh   = (const float*)d_in[4];
  const float* w_proj = (const float*)d_in[5];
  const float* b_proj = (const float*)d_in[6];
  const float* gamma  = (const float*)d_in[7];
  const float* beta   = (const float*)d_in[8];

  float* out = (float*)d_out;
  __half* gi = (__half*)d_ws;            // [B*T][384] f16 = 48 MB scratch

  gi_gemm<<<256, 512, 0, stream>>>(x, w_ih, b_ih, b_hh, gi);
  gru_scan<<<B_, 256, 0, stream>>>(gi, w_hh, b_hh, out);
  proj_ln<<<(B_ * T_) / PROJ_ROWS, 64, 0, stream>>>(out, w_proj, b_proj, gamma, beta);
}